// Round 3
// baseline (221.131 us; speedup 1.0000x reference)
//
#include <hip/hip_runtime.h>

#define BATCH   4096
#define IN_DIM  1024
#define OUT_DIM 1024
#define NB      8                 // DEGREE + 1
#define KD      (IN_DIM * NB)     // 8192

typedef __bf16 bf16x8 __attribute__((ext_vector_type(8)));
typedef float  f32x4  __attribute__((ext_vector_type(4)));
typedef unsigned short us8 __attribute__((ext_vector_type(8)));

__device__ __forceinline__ unsigned short f2bf(float f) {
    unsigned int u = __float_as_uint(f);
    u += 0x7fffu + ((u >> 16) & 1u);   // round-to-nearest-even
    return (unsigned short)(u >> 16);
}

// fast tanh: 1 - 2/(e^{2x}+1) via v_exp_f32 (2^x) + v_rcp_f32.
// Correct limits: x->+inf: exp2->inf, rcp->0, t->1; x->-inf: exp2->0, t->-1.
__device__ __forceinline__ float fast_tanh(float x) {
    const float LOG2E_X2 = 2.8853900817779268f;   // 2*log2(e)
    float e = __builtin_amdgcn_exp2f(x * LOG2E_X2);
    return 1.0f - 2.0f * __builtin_amdgcn_rcpf(e + 1.0f);
}

__device__ __forceinline__ void ld_lds16(const unsigned short* g, unsigned short* l) {
    __builtin_amdgcn_global_load_lds(
        (const __attribute__((address_space(1))) void*)g,
        (__attribute__((address_space(3))) void*)l, 16, 0, 0);
}

// ---------------------------------------------------------------------------
// Kernel 1: basis prep. A[b*KD + i*8 + d] = bf16(P_d(tanh(x[b,i])))
// ---------------------------------------------------------------------------
__global__ __launch_bounds__(256) void prep_basis(
    const float* __restrict__ x, const float* __restrict__ ap,
    const float* __restrict__ qp, unsigned short* __restrict__ Aw) {
    int idx = blockIdx.x * 256 + threadIdx.x;   // (b, i) flat, exact grid
    float a = ap[0], q = qp[0];
    float xt = fast_tanh(x[idx]);
    float p[NB];
    p[0] = 1.0f;
    p[1] = xt - a;
    float qn = q, qn1 = 1.0f;   // q^n, q^(n-1)
#pragma unroll
    for (int n = 2; n < NB; ++n) {
        qn *= q; qn1 *= q;
        p[n] = (xt - (a + qn)) * p[n - 1] - a * qn1 * p[n - 2];
    }
    us8 v;
#pragma unroll
    for (int d = 0; d < NB; ++d) v[d] = f2bf(p[d]);
    *(us8*)(Aw + (size_t)idx * NB) = v;   // 16B coalesced store
}

// ---------------------------------------------------------------------------
// Kernel 2: coeffs [I][O][8] fp32 -> Bt [O][KD] bf16 via LDS tile transpose.
// ---------------------------------------------------------------------------
#define TI 32
#define TO 64

__global__ __launch_bounds__(256) void repack_coeffs(
    const float* __restrict__ coeffs, unsigned short* __restrict__ Bt) {
    __shared__ __align__(16) unsigned short lt[TO * TI * NB];  // 32 KB
    const int tid = threadIdx.x;
    const int i0 = (blockIdx.x & 31) * TI;
    const int o0 = (blockIdx.x >> 5) * TO;

    {
        const int o_local = tid & 63;
        const int swz = o_local & 31;
#pragma unroll
        for (int pass = 0; pass < 8; ++pass) {
            const int i_local = pass * 4 + (tid >> 6);
            const float* src = coeffs +
                ((size_t)(i0 + i_local) * OUT_DIM + (o0 + o_local)) * NB;
            float4 v0 = *(const float4*)src;
            float4 v1 = *(const float4*)(src + 4);
            us8 v;
            v[0] = f2bf(v0.x); v[1] = f2bf(v0.y); v[2] = f2bf(v0.z); v[3] = f2bf(v0.w);
            v[4] = f2bf(v1.x); v[5] = f2bf(v1.y); v[6] = f2bf(v1.z); v[7] = f2bf(v1.w);
            *(us8*)(lt + o_local * (TI * NB) + (i_local ^ swz) * NB) = v;
        }
    }
    __syncthreads();
    {
        const int c = tid & 31;
#pragma unroll
        for (int pass = 0; pass < 8; ++pass) {
            const int o_local = pass * 8 + (tid >> 5);
            us8 v = *(const us8*)(lt + o_local * (TI * NB) + (c ^ (o_local & 31)) * NB);
            *(us8*)(Bt + (size_t)(o0 + o_local) * KD + (i0 + c) * NB) = v;
        }
    }
}

// ---------------------------------------------------------------------------
// Kernel 3: GEMM  C_part = A[M,KD] * Bt[N,KD]^T   (bf16 -> fp32, split-K x4)
// BM=BN=128 BK=32, 256 threads (2x2 waves, wave tile 64x64). Grid 1024 ->
// 4 blocks/CU for barrier-phase diversity. ATOMIC=false: partials to ws
// (deterministic, no L2 RMW); ATOMIC=true: atomicAdd into zeroed out.
// ---------------------------------------------------------------------------
#define BM 128
#define BN 128
#define BK 32
#define KSPLIT 4
#define KCH (KD / KSPLIT)   // 2048

template <bool ATOMIC>
__global__ __launch_bounds__(256, 4) void gemm_kernel(
    const unsigned short* __restrict__ A,    // bf16 bits [BATCH][KD]
    const unsigned short* __restrict__ Bt,   // bf16 bits [OUT_DIM][KD]
    float* __restrict__ C) {  // ATOMIC: [BATCH][OUT_DIM]; else [KSPLIT][BATCH][OUT_DIM]
    __shared__ __align__(16) unsigned short lA[BM * BK];  // 8 KB
    __shared__ __align__(16) unsigned short lB[BN * BK];  // 8 KB

    const int tid = threadIdx.x;
    const int bidx = blockIdx.x;
    const int chunk = bidx >> 5;            // 0..KSPLIT-1  (32 tile-blocks per chunk)
    const size_t kbase = (size_t)chunk * KCH;
    const int bn0 = (bidx & 7) * BN;
    const int bm0 = ((bidx & 31) >> 3) * BM + (chunk & 3) * 0; // tiles: 32 per chunk
    // NOTE: grid = KSPLIT * (M/BM) * (N/BN) = 4 * 4*... see launch: 4*256 wait
    // Actually (M/BM)*(N/BN) = 32*8 = 256? M/BM = 32, N/BN = 8 -> 256 per chunk.
    // Recompute properly below.
    (void)bm0;

    const int tiles = (BATCH / BM) * (OUT_DIM / BN);   // 256
    const int tIdx  = bidx & (tiles - 1);
    const int ch    = bidx / tiles;
    const size_t kb = (size_t)ch * KCH;
    const int n0 = (tIdx & 7) * BN;
    const int m0 = (tIdx >> 3) * BM;

    const int lane  = tid & 63;
    const int wid   = tid >> 6;
    const int wm    = (wid & 1) * 64;
    const int wn    = (wid >> 1) * 64;
    const int row16 = lane & 15;
    const int quad  = lane >> 4;

    int aOff[4], bOff[4];
#pragma unroll
    for (int mt = 0; mt < 4; ++mt) {
        int r = wm + mt * 16 + row16;
        aOff[mt] = r * BK + (quad ^ ((r >> 1) & 3)) * 8;
    }
#pragma unroll
    for (int nt = 0; nt < 4; ++nt) {
        int c = wn + nt * 16 + row16;
        bOff[nt] = c * BK + (quad ^ ((c >> 1) & 3)) * 8;
    }

    const int r0 = tid >> 2, p0 = tid & 3;
    const int r1 = r0 + 64;
    const unsigned short* gA0 = A + (size_t)(m0 + r0) * KD + kb + ((p0 ^ ((r0 >> 1) & 3)) * 8);
    const unsigned short* gA1 = A + (size_t)(m0 + r1) * KD + kb + ((p0 ^ ((r1 >> 1) & 3)) * 8);
    const unsigned short* gB0 = Bt + (size_t)(n0 + r0) * KD + kb + ((p0 ^ ((r0 >> 1) & 3)) * 8);
    const unsigned short* gB1 = Bt + (size_t)(n0 + r1) * KD + kb + ((p0 ^ ((r1 >> 1) & 3)) * 8);
    unsigned short* dA0 = lA + tid * 8;
    unsigned short* dA1 = lA + (tid + 256) * 8;
    unsigned short* dB0 = lB + tid * 8;
    unsigned short* dB1 = lB + (tid + 256) * 8;

    f32x4 acc[4][4] = {};

    for (int k0 = 0; k0 < KCH; k0 += BK) {
        ld_lds16(gA0 + k0, dA0);
        ld_lds16(gA1 + k0, dA1);
        ld_lds16(gB0 + k0, dB0);
        ld_lds16(gB1 + k0, dB1);
        __syncthreads();

        bf16x8 aF[4], bF[4];
#pragma unroll
        for (int mt = 0; mt < 4; ++mt) aF[mt] = *(const bf16x8*)(lA + aOff[mt]);
#pragma unroll
        for (int nt = 0; nt < 4; ++nt) bF[nt] = *(const bf16x8*)(lB + bOff[nt]);
#pragma unroll
        for (int mt = 0; mt < 4; ++mt)
#pragma unroll
            for (int nt = 0; nt < 4; ++nt)
                acc[mt][nt] = __builtin_amdgcn_mfma_f32_16x16x32_bf16(
                    aF[mt], bF[nt], acc[mt][nt], 0, 0, 0);
        __syncthreads();
    }

    float* Cb = ATOMIC ? C : C + (size_t)ch * BATCH * OUT_DIM;
    // C/D layout (m89-verified): col = lane&15, row = quad*4 + reg
#pragma unroll
    for (int mt = 0; mt < 4; ++mt) {
        const int rbase = m0 + wm + mt * 16 + quad * 4;
#pragma unroll
        for (int nt = 0; nt < 4; ++nt) {
            const int col = n0 + wn + nt * 16 + row16;
#pragma unroll
            for (int r = 0; r < 4; ++r) {
                if (ATOMIC)
                    atomicAdd(&Cb[(size_t)(rbase + r) * OUT_DIM + col], acc[mt][nt][r]);
                else
                    Cb[(size_t)(rbase + r) * OUT_DIM + col] = acc[mt][nt][r];
            }
        }
    }
}

// ---------------------------------------------------------------------------
// Kernel 4: reduce KSPLIT partial buffers -> out. 80 MB traffic, ~13 us.
// ---------------------------------------------------------------------------
__global__ __launch_bounds__(256) void reduce_partials(
    const float* __restrict__ P, float* __restrict__ out) {
    const size_t S = (size_t)BATCH * OUT_DIM;        // elements per partial
    size_t idx = ((size_t)blockIdx.x * 256 + threadIdx.x) * 4;
    f32x4 s = *(const f32x4*)(P + idx);
#pragma unroll
    for (int c = 1; c < KSPLIT; ++c) {
        f32x4 v = *(const f32x4*)(P + c * S + idx);
        s = s + v;
    }
    *(f32x4*)(out + idx) = s;
}

// ---------------------------------------------------------------------------
// Fallback (only if ws too small): fp32, block per batch row, basis in LDS.
// ---------------------------------------------------------------------------
__global__ __launch_bounds__(256) void fallback_kernel(
    const float* __restrict__ x, const float* __restrict__ ap,
    const float* __restrict__ qp, const float* __restrict__ coeffs,
    float* __restrict__ out) {
    __shared__ float sb[IN_DIM][NB];   // 32 KB
    const int b = blockIdx.x;
    const float a = ap[0], q = qp[0];
    for (int i = threadIdx.x; i < IN_DIM; i += 256) {
        float xt = fast_tanh(x[(size_t)b * IN_DIM + i]);
        float p0 = 1.0f, p1 = xt - a;
        sb[i][0] = p0; sb[i][1] = p1;
        float qn = q, qn1 = 1.0f;
#pragma unroll
        for (int n = 2; n < NB; ++n) {
            qn *= q; qn1 *= q;
            float p2 = (xt - (a + qn)) * p1 - a * qn1 * p0;
            sb[i][n] = p2;
            p0 = p1; p1 = p2;
        }
    }
    __syncthreads();
    float acc[4] = {0.f, 0.f, 0.f, 0.f};
    for (int i = 0; i < IN_DIM; ++i) {
        float bb[NB];
#pragma unroll
        for (int d = 0; d < NB; ++d) bb[d] = sb[i][d];
#pragma unroll
        for (int j = 0; j < 4; ++j) {
            int o = threadIdx.x + j * 256;
            const float* cf = coeffs + ((size_t)i * OUT_DIM + o) * NB;
            float s = 0.f;
#pragma unroll
            for (int d = 0; d < NB; ++d) s += bb[d] * cf[d];
            acc[j] += s;
        }
    }
#pragma unroll
    for (int j = 0; j < 4; ++j)
        out[(size_t)b * OUT_DIM + threadIdx.x + j * 256] = acc[j];
}

// ---------------------------------------------------------------------------
extern "C" void kernel_launch(void* const* d_in, const int* in_sizes, int n_in,
                              void* d_out, int out_size, void* d_ws, size_t ws_size,
                              hipStream_t stream) {
    const float* x      = (const float*)d_in[0];
    const float* a      = (const float*)d_in[1];
    const float* q      = (const float*)d_in[2];
    const float* coeffs = (const float*)d_in[3];
    float* out = (float*)d_out;

    const size_t needA = (size_t)BATCH * KD * sizeof(unsigned short);   // 64 MB
    const size_t needB = (size_t)OUT_DIM * KD * sizeof(unsigned short); // 16 MB
    const size_t needP = (size_t)KSPLIT * BATCH * OUT_DIM * sizeof(float); // 64 MB
    const int tiles = (BATCH / BM) * (OUT_DIM / BN);   // 256

    if (ws_size >= needA + needB + needP) {
        unsigned short* Aw = (unsigned short*)d_ws;
        unsigned short* Bt = Aw + (size_t)BATCH * KD;
        float* P = (float*)((char*)d_ws + needA + needB);
        prep_basis<<<BATCH * IN_DIM / 256, 256, 0, stream>>>(x, a, q, Aw);
        repack_coeffs<<<(IN_DIM / TI) * (OUT_DIM / TO), 256, 0, stream>>>(coeffs, Bt);
        gemm_kernel<false><<<tiles * KSPLIT, 256, 0, stream>>>(Aw, Bt, P);
        reduce_partials<<<BATCH * OUT_DIM / 1024, 256, 0, stream>>>(P, out);
    } else if (ws_size >= needA + needB) {
        unsigned short* Aw = (unsigned short*)d_ws;
        unsigned short* Bt = Aw + (size_t)BATCH * KD;
        prep_basis<<<BATCH * IN_DIM / 256, 256, 0, stream>>>(x, a, q, Aw);
        repack_coeffs<<<(IN_DIM / TI) * (OUT_DIM / TO), 256, 0, stream>>>(coeffs, Bt);
        hipMemsetAsync(out, 0, (size_t)out_size * sizeof(float), stream);
        gemm_kernel<true><<<tiles * KSPLIT, 256, 0, stream>>>(Aw, Bt, out);
    } else {
        fallback_kernel<<<BATCH, 256, 0, stream>>>(x, a, q, coeffs, out);
    }
}

// Round 4
// 210.878 us; speedup vs baseline: 1.0486x; 1.0486x over previous
//
#include <hip/hip_runtime.h>

#define BATCH   4096
#define IN_DIM  1024
#define OUT_DIM 1024
#define NB      8                 // DEGREE + 1
#define KD      (IN_DIM * NB)     // 8192

typedef __bf16 bf16x8 __attribute__((ext_vector_type(8)));
typedef float  f32x4  __attribute__((ext_vector_type(4)));
typedef unsigned short us8 __attribute__((ext_vector_type(8)));

__device__ __forceinline__ unsigned short f2bf(float f) {
    unsigned int u = __float_as_uint(f);
    u += 0x7fffu + ((u >> 16) & 1u);   // round-to-nearest-even
    return (unsigned short)(u >> 16);
}

// fast tanh: 1 - 2/(e^{2x}+1) via v_exp_f32 + v_rcp_f32; exact limits at +-inf.
__device__ __forceinline__ float fast_tanh(float x) {
    const float LOG2E_X2 = 2.8853900817779268f;   // 2*log2(e)
    float e = __builtin_amdgcn_exp2f(x * LOG2E_X2);
    return 1.0f - 2.0f * __builtin_amdgcn_rcpf(e + 1.0f);
}

__device__ __forceinline__ void ld_lds16(const unsigned short* g, unsigned short* l) {
    __builtin_amdgcn_global_load_lds(
        (const __attribute__((address_space(1))) void*)g,
        (__attribute__((address_space(3))) void*)l, 16, 0, 0);
}

// ---------------------------------------------------------------------------
// Kernel 1 (fused): blocks [0,16384) do basis prep; blocks [16384,16896) do
// the coeffs transpose-repack. Independent work, one dispatch.
//   prep:   A[b*KD + i*8 + d] = bf16(P_d(tanh(x[b,i])))
//   repack: Bt[o][i*8+d] = bf16(coeffs[i][o][d])  via LDS tile transpose
// ---------------------------------------------------------------------------
#define PREP_BLOCKS (BATCH * IN_DIM / 256)   // 16384
#define TI 32
#define TO 64

__global__ __launch_bounds__(256) void prep_and_repack(
    const float* __restrict__ x, const float* __restrict__ ap,
    const float* __restrict__ qp, const float* __restrict__ coeffs,
    unsigned short* __restrict__ Aw, unsigned short* __restrict__ Bt) {
    __shared__ __align__(16) unsigned short lt[TO * TI * NB];  // 32 KB (repack only)
    const int tid = threadIdx.x;

    if (blockIdx.x < PREP_BLOCKS) {
        int idx = blockIdx.x * 256 + tid;
        float a = ap[0], q = qp[0];
        float xt = fast_tanh(x[idx]);
        float p[NB];
        p[0] = 1.0f;
        p[1] = xt - a;
        float qn = q, qn1 = 1.0f;
#pragma unroll
        for (int n = 2; n < NB; ++n) {
            qn *= q; qn1 *= q;
            p[n] = (xt - (a + qn)) * p[n - 1] - a * qn1 * p[n - 2];
        }
        us8 v;
#pragma unroll
        for (int d = 0; d < NB; ++d) v[d] = f2bf(p[d]);
        *(us8*)(Aw + (size_t)idx * NB) = v;
        return;
    }

    const int bid = blockIdx.x - PREP_BLOCKS;
    const int i0 = (bid & 31) * TI;
    const int o0 = (bid >> 5) * TO;
    {
        const int o_local = tid & 63;
        const int swz = o_local & 31;
#pragma unroll
        for (int pass = 0; pass < 8; ++pass) {
            const int i_local = pass * 4 + (tid >> 6);
            const float* src = coeffs +
                ((size_t)(i0 + i_local) * OUT_DIM + (o0 + o_local)) * NB;
            float4 v0 = *(const float4*)src;
            float4 v1 = *(const float4*)(src + 4);
            us8 v;
            v[0] = f2bf(v0.x); v[1] = f2bf(v0.y); v[2] = f2bf(v0.z); v[3] = f2bf(v0.w);
            v[4] = f2bf(v1.x); v[5] = f2bf(v1.y); v[6] = f2bf(v1.z); v[7] = f2bf(v1.w);
            *(us8*)(lt + o_local * (TI * NB) + (i_local ^ swz) * NB) = v;
        }
    }
    __syncthreads();
    {
        const int c = tid & 31;
#pragma unroll
        for (int pass = 0; pass < 8; ++pass) {
            const int o_local = pass * 8 + (tid >> 5);
            us8 v = *(const us8*)(lt + o_local * (TI * NB) + (c ^ (o_local & 31)) * NB);
            *(us8*)(Bt + (size_t)(o0 + o_local) * KD + (i0 + c) * NB) = v;
        }
    }
}

// ---------------------------------------------------------------------------
// Kernel 2: GEMM  C[M,N] += A[M,KD] * Bt[N,KD]^T  (bf16 -> fp32, split-K x4,
// atomicAdd into zeroed C). BM=BN=128, BK=64, 256 thr (2x2 waves, 64x64 wave
// tile). Grid 1024 -> 4 blocks/CU. XCD mapping: bidx&7 = m mod 8, so each XCD
// sees 4 m-tiles of A (8 MB) + all of B (4 MB per chunk = its L2), and all 4
// K-chunks of a tile share an XCD (atomics stay in one L2).
// LDS swizzle: row r (128 B = 8 chunks) stores logical k-chunk s at slot
// s ^ (r & 7)  -> every ds_read_b128 hits all 32 banks uniformly.
// ---------------------------------------------------------------------------
#define BM 128
#define BN 128
#define BK 64
#define KSPLIT 4
#define KCH (KD / KSPLIT)   // 2048

__global__ __launch_bounds__(256, 4) void gemm_kernel(
    const unsigned short* __restrict__ A,    // bf16 bits [BATCH][KD]
    const unsigned short* __restrict__ Bt,   // bf16 bits [OUT_DIM][KD]
    float* __restrict__ C) {                 // [BATCH][OUT_DIM], pre-zeroed
    __shared__ __align__(16) unsigned short lA[BM * BK];  // 16 KB
    __shared__ __align__(16) unsigned short lB[BN * BK];  // 16 KB

    const int tid  = threadIdx.x;
    const int bidx = blockIdx.x;
    const int m0 = (((bidx >> 3) & 3) * 8 + (bidx & 7)) * BM;  // low3 -> XCD
    const int n0 = ((bidx >> 5) & 7) * BN;
    const int ch = bidx >> 8;
    const size_t kb = (size_t)ch * KCH;

    const int lane  = tid & 63;
    const int wid   = tid >> 6;
    const int wm    = (wid & 1) * 64;
    const int wn    = (wid >> 1) * 64;
    const int row16 = lane & 15;
    const int quad  = lane >> 4;

    // ds_read element offsets for kk=0 (k in [0,32)); kk=1 is ^32 (chunk ^4).
    int aOff[4], bOff[4];
#pragma unroll
    for (int mt = 0; mt < 4; ++mt) {
        int r = wm + mt * 16 + row16;
        aOff[mt] = r * BK + ((quad ^ (r & 7)) * 8);
    }
#pragma unroll
    for (int nt = 0; nt < 4; ++nt) {
        int c = wn + nt * 16 + row16;
        bOff[nt] = c * BK + ((quad ^ (c & 7)) * 8);
    }

    // Staging: tile = 1024 x 16B chunks; thread t handles chunks t + 256*j.
    // Phys chunk c -> row r = c>>3, slot s = c&7; global k-chunk = s ^ (r&7).
    // Chunks t+256*j differ by exactly 32 rows (r&7 unchanged) -> +32*KD elems.
    const int r0 = tid >> 3, s0 = tid & 7;
    const unsigned short* gA0 = A  + (size_t)(m0 + r0) * KD + kb + ((s0 ^ (r0 & 7)) * 8);
    const unsigned short* gB0 = Bt + (size_t)(n0 + r0) * KD + kb + ((s0 ^ (r0 & 7)) * 8);
    unsigned short* dA = lA + tid * 8;
    unsigned short* dB = lB + tid * 8;

    f32x4 acc[4][4] = {};

    for (int k0 = 0; k0 < KCH; k0 += BK) {
#pragma unroll
        for (int j = 0; j < 4; ++j)
            ld_lds16(gA0 + k0 + (size_t)j * 32 * KD, dA + j * 2048);
#pragma unroll
        for (int j = 0; j < 4; ++j)
            ld_lds16(gB0 + k0 + (size_t)j * 32 * KD, dB + j * 2048);
        __syncthreads();

#pragma unroll
        for (int kk = 0; kk < 2; ++kk) {
            const int xo = kk * 32;
            bf16x8 aF[4], bF[4];
#pragma unroll
            for (int mt = 0; mt < 4; ++mt) aF[mt] = *(const bf16x8*)(lA + (aOff[mt] ^ xo));
#pragma unroll
            for (int nt = 0; nt < 4; ++nt) bF[nt] = *(const bf16x8*)(lB + (bOff[nt] ^ xo));
#pragma unroll
            for (int mt = 0; mt < 4; ++mt)
#pragma unroll
                for (int nt = 0; nt < 4; ++nt)
                    acc[mt][nt] = __builtin_amdgcn_mfma_f32_16x16x32_bf16(
                        aF[mt], bF[nt], acc[mt][nt], 0, 0, 0);
        }
        __syncthreads();
    }

    // C/D layout (m89-verified): col = lane&15, row = quad*4 + reg
#pragma unroll
    for (int mt = 0; mt < 4; ++mt) {
        const int rbase = m0 + wm + mt * 16 + quad * 4;
#pragma unroll
        for (int nt = 0; nt < 4; ++nt) {
            const int col = n0 + wn + nt * 16 + row16;
#pragma unroll
            for (int r = 0; r < 4; ++r)
                atomicAdd(&C[(size_t)(rbase + r) * OUT_DIM + col], acc[mt][nt][r]);
        }
    }
}

// ---------------------------------------------------------------------------
// Fallback (only if ws too small): fp32, block per batch row, basis in LDS.
// ---------------------------------------------------------------------------
__global__ __launch_bounds__(256) void fallback_kernel(
    const float* __restrict__ x, const float* __restrict__ ap,
    const float* __restrict__ qp, const float* __restrict__ coeffs,
    float* __restrict__ out) {
    __shared__ float sb[IN_DIM][NB];   // 32 KB
    const int b = blockIdx.x;
    const float a = ap[0], q = qp[0];
    for (int i = threadIdx.x; i < IN_DIM; i += 256) {
        float xt = fast_tanh(x[(size_t)b * IN_DIM + i]);
        float p0 = 1.0f, p1 = xt - a;
        sb[i][0] = p0; sb[i][1] = p1;
        float qn = q, qn1 = 1.0f;
#pragma unroll
        for (int n = 2; n < NB; ++n) {
            qn *= q; qn1 *= q;
            float p2 = (xt - (a + qn)) * p1 - a * qn1 * p0;
            sb[i][n] = p2;
            p0 = p1; p1 = p2;
        }
    }
    __syncthreads();
    float acc[4] = {0.f, 0.f, 0.f, 0.f};
    for (int i = 0; i < IN_DIM; ++i) {
        float bb[NB];
#pragma unroll
        for (int d = 0; d < NB; ++d) bb[d] = sb[i][d];
#pragma unroll
        for (int j = 0; j < 4; ++j) {
            int o = threadIdx.x + j * 256;
            const float* cf = coeffs + ((size_t)i * OUT_DIM + o) * NB;
            float s = 0.f;
#pragma unroll
            for (int d = 0; d < NB; ++d) s += bb[d] * cf[d];
            acc[j] += s;
        }
    }
#pragma unroll
    for (int j = 0; j < 4; ++j)
        out[(size_t)b * OUT_DIM + threadIdx.x + j * 256] = acc[j];
}

// ---------------------------------------------------------------------------
extern "C" void kernel_launch(void* const* d_in, const int* in_sizes, int n_in,
                              void* d_out, int out_size, void* d_ws, size_t ws_size,
                              hipStream_t stream) {
    const float* x      = (const float*)d_in[0];
    const float* a      = (const float*)d_in[1];
    const float* q      = (const float*)d_in[2];
    const float* coeffs = (const float*)d_in[3];
    float* out = (float*)d_out;

    const size_t needA = (size_t)BATCH * KD * sizeof(unsigned short);   // 64 MB
    const size_t needB = (size_t)OUT_DIM * KD * sizeof(unsigned short); // 16 MB
    const int repack_blocks = (IN_DIM / TI) * (OUT_DIM / TO);           // 512

    if (ws_size >= needA + needB) {
        unsigned short* Aw = (unsigned short*)d_ws;
        unsigned short* Bt = Aw + (size_t)BATCH * KD;
        hipMemsetAsync(out, 0, (size_t)out_size * sizeof(float), stream);
        prep_and_repack<<<PREP_BLOCKS + repack_blocks, 256, 0, stream>>>(
            x, a, q, coeffs, Aw, Bt);
        gemm_kernel<<<(BATCH / BM) * (OUT_DIM / BN) * KSPLIT, 256, 0, stream>>>(
            Aw, Bt, out);
    } else {
        fallback_kernel<<<BATCH, 256, 0, stream>>>(x, a, q, coeffs, out);
    }
}

// Round 5
// 204.875 us; speedup vs baseline: 1.0793x; 1.0293x over previous
//
#include <hip/hip_runtime.h>

#define BATCH   4096
#define IN_DIM  1024
#define OUT_DIM 1024
#define NB      8                 // DEGREE + 1
#define NBK     7                 // basis funcs in the GEMM (d=1..7; d=0 is a bias)
#define KD2     (IN_DIM * NBK)    // 7168

typedef __bf16 bf16x8 __attribute__((ext_vector_type(8)));
typedef float  f32x4  __attribute__((ext_vector_type(4)));
typedef unsigned short us8 __attribute__((ext_vector_type(8)));

__device__ __forceinline__ unsigned short f2bf(float f) {
    unsigned int u = __float_as_uint(f);
    u += 0x7fffu + ((u >> 16) & 1u);   // round-to-nearest-even
    return (unsigned short)(u >> 16);
}

// fast tanh: 1 - 2/(e^{2x}+1) via v_exp_f32 + v_rcp_f32; exact limits at +-inf.
__device__ __forceinline__ float fast_tanh(float x) {
    const float LOG2E_X2 = 2.8853900817779268f;   // 2*log2(e)
    float e = __builtin_amdgcn_exp2f(x * LOG2E_X2);
    return 1.0f - 2.0f * __builtin_amdgcn_rcpf(e + 1.0f);
}

__device__ __forceinline__ void ld_lds16(const unsigned short* g, unsigned short* l) {
    __builtin_amdgcn_global_load_lds(
        (const __attribute__((address_space(1))) void*)g,
        (__attribute__((address_space(3))) void*)l, 16, 0, 0);
}

// ---------------------------------------------------------------------------
// Kernel 1 (fused, 3 block roles in one dispatch):
//  [0, 16384):            basis prep  A[b][i*7+d-1] = bf16(P_d(tanh(x[b,i])))
//  [16384, 16896):        coeffs repack Bt[o][i*7+d-1] = bf16(coeffs[i][o][d])
//                         + exact fp32 bias partials bias_part[i/32][o]
//  [16896, 17920):        zero C (replaces the separate hipMemsetAsync)
// ---------------------------------------------------------------------------
#define PREP_BLOCKS   (BATCH * IN_DIM / 256)   // 16384
#define REPACK_BLOCKS 512
#define ZERO_BLOCKS   (BATCH * OUT_DIM / 4096) // 1024
#define TI 32
#define TO 64
#define RSTR 232    // LDS row stride (ushorts) per o: 224 data + 8 pad (16B-aligned)

__global__ __launch_bounds__(256) void prep_and_repack(
    const float* __restrict__ x, const float* __restrict__ ap,
    const float* __restrict__ qp, const float* __restrict__ coeffs,
    unsigned short* __restrict__ Aw, unsigned short* __restrict__ Bt,
    float* __restrict__ bias_part,   // [32][OUT_DIM]
    float* __restrict__ C) {
    __shared__ __align__(16) unsigned short lt[TO * RSTR + 512];  // 30.0 KB
    const int tid = threadIdx.x;

    if (blockIdx.x < PREP_BLOCKS) {
        // ---- basis prep: block covers (b, i0..i0+255) ----
        const int b  = blockIdx.x >> 2;
        const int i0 = (blockIdx.x & 3) << 8;
        const float a = ap[0], q = qp[0];
        const float xt = fast_tanh(x[(size_t)b * IN_DIM + i0 + tid]);
        float p[NB];
        p[0] = 1.0f;
        p[1] = xt - a;
        float qn = q, qn1 = 1.0f;
#pragma unroll
        for (int n = 2; n < NB; ++n) {
            qn *= q; qn1 *= q;
            p[n] = (xt - (a + qn)) * p[n - 1] - a * qn1 * p[n - 2];
        }
        // pack 7 bf16/thread via LDS, then 16B-coalesced global stores
#pragma unroll
        for (int d = 1; d < NB; ++d) lt[tid * 7 + (d - 1)] = f2bf(p[d]);
        __syncthreads();
        if (tid < 224) {   // 224 chunks x 16 B = 256*7 ushorts
            us8 v = *(const us8*)(lt + tid * 8);
            *(us8*)(Aw + (size_t)b * KD2 + i0 * 7 + tid * 8) = v;
        }
        return;
    }

    const int bid = blockIdx.x - PREP_BLOCKS;
    if (bid < REPACK_BLOCKS) {
        // ---- repack + bias partials: patch i0..i0+32 x o0..o0+64 ----
        const int g  = bid & 31;
        const int i0 = g * TI;
        const int o0 = (bid >> 5) * TO;
        const int o_local = tid & 63;
        float bpart = 0.f;
#pragma unroll
        for (int pass = 0; pass < 8; ++pass) {
            const int i_local = pass * 4 + (tid >> 6);
            const float* src = coeffs +
                ((size_t)(i0 + i_local) * OUT_DIM + (o0 + o_local)) * NB;
            float4 v0 = *(const float4*)src;
            float4 v1 = *(const float4*)(src + 4);
            bpart += v0.x;                       // d = 0 -> exact fp32 bias
            unsigned short* dst = lt + o_local * RSTR + i_local * 7;
            dst[0] = f2bf(v0.y); dst[1] = f2bf(v0.z); dst[2] = f2bf(v0.w);
            dst[3] = f2bf(v1.x); dst[4] = f2bf(v1.y); dst[5] = f2bf(v1.z);
            dst[6] = f2bf(v1.w);
        }
        float* sb = (float*)(lt + TO * RSTR);    // 256 floats
        sb[(tid >> 6) * 64 + o_local] = bpart;
        __syncthreads();
        if (tid < 64)
            bias_part[(size_t)g * OUT_DIM + o0 + tid] =
                sb[tid] + sb[64 + tid] + sb[128 + tid] + sb[192 + tid];
        // write phase: thread -> (o = tid>>2, chunk c = (tid&3)+4*pass)
#pragma unroll
        for (int pass = 0; pass < 7; ++pass) {
            const int o = tid >> 2;
            const int c = (tid & 3) + 4 * pass;  // 28 chunks x 16 B = 224 ushorts
            us8 v = *(const us8*)(lt + o * RSTR + c * 8);
            *(us8*)(Bt + (size_t)(o0 + o) * KD2 + i0 * 7 + c * 8) = v;
        }
        return;
    }

    // ---- zero C: 4096 floats per block ----
    const int z = bid - REPACK_BLOCKS;
    float* dst = C + (size_t)z * 4096 + tid * 4;
    const f32x4 zero = {0.f, 0.f, 0.f, 0.f};
#pragma unroll
    for (int j = 0; j < 4; ++j) *(f32x4*)(dst + j * 1024) = zero;
}

// ---------------------------------------------------------------------------
// Kernel 2: GEMM  C[M,N] += A[M,KD2] * Bt[N,KD2]^T  (bf16 -> fp32, split-K x4,
// atomicAdd into zeroed C; ch==0 blocks also add the exact d=0 bias).
// BM=BN=128, BK=64, 256 thr (2x2 waves, 64x64 wave tile). Grid 1024 ->
// 4 blocks/CU. XCD mapping: bidx&7 = m mod 8 (A slice per XCD) and all 4
// K-chunks of a tile share an XCD (atomics resolve in one L2).
// LDS swizzle: row r stores logical k-chunk s at slot s ^ (r & 7).
// ---------------------------------------------------------------------------
#define BM 128
#define BN 128
#define BK 64
#define KSPLIT 4
#define KCH (KD2 / KSPLIT)   // 1792 -> 28 iters of BK=64

__global__ __launch_bounds__(256, 4) void gemm_kernel(
    const unsigned short* __restrict__ A,    // bf16 bits [BATCH][KD2]
    const unsigned short* __restrict__ Bt,   // bf16 bits [OUT_DIM][KD2]
    const float* __restrict__ bias_part,     // [32][OUT_DIM]
    float* __restrict__ C) {                 // [BATCH][OUT_DIM], pre-zeroed
    __shared__ __align__(16) unsigned short lA[BM * BK];  // 16 KB
    __shared__ __align__(16) unsigned short lB[BN * BK];  // 16 KB

    const int tid  = threadIdx.x;
    const int bidx = blockIdx.x;
    const int m0 = (((bidx >> 3) & 3) * 8 + (bidx & 7)) * BM;  // low3 -> XCD
    const int n0 = ((bidx >> 5) & 7) * BN;
    const int ch = bidx >> 8;
    const size_t kb = (size_t)ch * KCH;

    const int lane  = tid & 63;
    const int wid   = tid >> 6;
    const int wm    = (wid & 1) * 64;
    const int wn    = (wid >> 1) * 64;
    const int row16 = lane & 15;
    const int quad  = lane >> 4;

    // ds_read element offsets for kk=0; kk=1 is ^32 elems (chunk ^4).
    int aOff[4], bOff[4];
#pragma unroll
    for (int mt = 0; mt < 4; ++mt) {
        int r = wm + mt * 16 + row16;
        aOff[mt] = r * BK + ((quad ^ (r & 7)) * 8);
    }
#pragma unroll
    for (int nt = 0; nt < 4; ++nt) {
        int c = wn + nt * 16 + row16;
        bOff[nt] = c * BK + ((quad ^ (c & 7)) * 8);
    }

    // Staging: tile = 1024 x 16B chunks; thread t -> chunks t + 256*j.
    // Phys chunk c: row r = c>>3, slot s = c&7, global k-chunk = s ^ (r&7).
    const int r0 = tid >> 3, s0 = tid & 7;
    const unsigned short* gA0 = A  + (size_t)(m0 + r0) * KD2 + kb + ((s0 ^ (r0 & 7)) * 8);
    const unsigned short* gB0 = Bt + (size_t)(n0 + r0) * KD2 + kb + ((s0 ^ (r0 & 7)) * 8);
    unsigned short* dA = lA + tid * 8;
    unsigned short* dB = lB + tid * 8;

    f32x4 acc[4][4] = {};

    for (int k0 = 0; k0 < KCH; k0 += BK) {
#pragma unroll
        for (int j = 0; j < 4; ++j)
            ld_lds16(gA0 + k0 + (size_t)j * 32 * KD2, dA + j * 2048);
#pragma unroll
        for (int j = 0; j < 4; ++j)
            ld_lds16(gB0 + k0 + (size_t)j * 32 * KD2, dB + j * 2048);
        __syncthreads();

#pragma unroll
        for (int kk = 0; kk < 2; ++kk) {
            const int xo = kk * 32;
            bf16x8 aF[4], bF[4];
#pragma unroll
            for (int mt = 0; mt < 4; ++mt) aF[mt] = *(const bf16x8*)(lA + (aOff[mt] ^ xo));
#pragma unroll
            for (int nt = 0; nt < 4; ++nt) bF[nt] = *(const bf16x8*)(lB + (bOff[nt] ^ xo));
#pragma unroll
            for (int mt = 0; mt < 4; ++mt)
#pragma unroll
                for (int nt = 0; nt < 4; ++nt)
                    acc[mt][nt] = __builtin_amdgcn_mfma_f32_16x16x32_bf16(
                        aF[mt], bF[nt], acc[mt][nt], 0, 0, 0);
        }
        __syncthreads();
    }

    // ch==0 blocks fold in the exact d=0 bias: sbias[col] = sum_g bias_part[g][col]
    if (ch == 0) {
        float* sb = (float*)lA;   // safe: loop ended with __syncthreads
        if (tid < BN) {
            float s = 0.f;
#pragma unroll
            for (int g = 0; g < 32; ++g) s += bias_part[(size_t)g * OUT_DIM + n0 + tid];
            sb[tid] = s;
        }
        __syncthreads();
    }
    const float* sb = (const float*)lA;

    // C/D layout (m89-verified): col = lane&15, row = quad*4 + reg
#pragma unroll
    for (int mt = 0; mt < 4; ++mt) {
        const int rbase = m0 + wm + mt * 16 + quad * 4;
#pragma unroll
        for (int nt = 0; nt < 4; ++nt) {
            const int col = n0 + wn + nt * 16 + row16;
            const float bv = (ch == 0) ? sb[wn + nt * 16 + row16] : 0.f;
#pragma unroll
            for (int r = 0; r < 4; ++r)
                atomicAdd(&C[(size_t)(rbase + r) * OUT_DIM + col], acc[mt][nt][r] + bv);
        }
    }
}

// ---------------------------------------------------------------------------
// Fallback (only if ws too small): fp32, block per batch row, basis in LDS.
// ---------------------------------------------------------------------------
__global__ __launch_bounds__(256) void fallback_kernel(
    const float* __restrict__ x, const float* __restrict__ ap,
    const float* __restrict__ qp, const float* __restrict__ coeffs,
    float* __restrict__ out) {
    __shared__ float sb[IN_DIM][NB];   // 32 KB
    const int b = blockIdx.x;
    const float a = ap[0], q = qp[0];
    for (int i = threadIdx.x; i < IN_DIM; i += 256) {
        float xt = fast_tanh(x[(size_t)b * IN_DIM + i]);
        float p0 = 1.0f, p1 = xt - a;
        sb[i][0] = p0; sb[i][1] = p1;
        float qn = q, qn1 = 1.0f;
#pragma unroll
        for (int n = 2; n < NB; ++n) {
            qn *= q; qn1 *= q;
            float p2 = (xt - (a + qn)) * p1 - a * qn1 * p0;
            sb[i][n] = p2;
            p0 = p1; p1 = p2;
        }
    }
    __syncthreads();
    float acc[4] = {0.f, 0.f, 0.f, 0.f};
    for (int i = 0; i < IN_DIM; ++i) {
        float bb[NB];
#pragma unroll
        for (int d = 0; d < NB; ++d) bb[d] = sb[i][d];
#pragma unroll
        for (int j = 0; j < 4; ++j) {
            int o = threadIdx.x + j * 256;
            const float* cf = coeffs + ((size_t)i * OUT_DIM + o) * NB;
            float s = 0.f;
#pragma unroll
            for (int d = 0; d < NB; ++d) s += bb[d] * cf[d];
            acc[j] += s;
        }
    }
#pragma unroll
    for (int j = 0; j < 4; ++j)
        out[(size_t)b * OUT_DIM + threadIdx.x + j * 256] = acc[j];
}

// ---------------------------------------------------------------------------
extern "C" void kernel_launch(void* const* d_in, const int* in_sizes, int n_in,
                              void* d_out, int out_size, void* d_ws, size_t ws_size,
                              hipStream_t stream) {
    const float* x      = (const float*)d_in[0];
    const float* a      = (const float*)d_in[1];
    const float* q      = (const float*)d_in[2];
    const float* coeffs = (const float*)d_in[3];
    float* out = (float*)d_out;

    const size_t needA = (size_t)BATCH * KD2 * sizeof(unsigned short);   // 56 MB
    const size_t needB = (size_t)OUT_DIM * KD2 * sizeof(unsigned short); // 14 MB
    const size_t needBias = 32 * (size_t)OUT_DIM * sizeof(float);        // 128 KB

    if (ws_size >= needA + needB + needBias) {
        unsigned short* Aw = (unsigned short*)d_ws;
        unsigned short* Bt = Aw + (size_t)BATCH * KD2;
        float* bias_part = (float*)((char*)d_ws + needA + needB);
        prep_and_repack<<<PREP_BLOCKS + REPACK_BLOCKS + ZERO_BLOCKS, 256, 0, stream>>>(
            x, a, q, coeffs, Aw, Bt, bias_part, out);
        gemm_kernel<<<(BATCH / BM) * (OUT_DIM / BN) * KSPLIT, 256, 0, stream>>>(
            Aw, Bt, bias_part, out);
    } else {
        fallback_kernel<<<BATCH, 256, 0, stream>>>(x, a, q, coeffs, out);
    }
}